// Round 1
// baseline (153.370 us; speedup 1.0000x reference)
//
#include <hip/hip_runtime.h>
#include <math.h>

#define IDIM 160
#define GDIM 161
#define NB_SAMPLES 64
#define NB_RAYS 32768
#define NCELL (GDIM * GDIM * GDIM)  // 4173281

// ---------------- Threefry2x32 (JAX-compatible) ----------------
__device__ __forceinline__ unsigned rotl32(unsigned x, unsigned d) {
    return (x << d) | (x >> (32u - d));
}

__device__ __forceinline__ void tf_round(unsigned& x0, unsigned& x1, unsigned r) {
    x0 += x1;
    x1 = rotl32(x1, r);
    x1 ^= x0;
}

// JAX partitionable path, 32-bit width:
//   per flat index i: (o0,o1) = threefry2x32(key=(0,42), ctr=(hi=0, lo=i))
//   bits = o0 ^ o1
// (If the harness JAX predates the partitionable default flip, switch to the
//  "original" indexing: bits[i] = o0 of threefry((0,42),(i, i+N/2)) for i<N/2,
//  o1 of threefry((0,42),(i-N/2, i)) otherwise, N = 2^21.)
__device__ __forceinline__ unsigned jax_random_bits(unsigned idx) {
    const unsigned k0 = 0u, k1 = 42u;
    const unsigned ks2 = k0 ^ k1 ^ 0x1BD11BDAu;
    unsigned x0 = 0u + k0;    // counts_hi + ks0
    unsigned x1 = idx + k1;   // counts_lo + ks1
    tf_round(x0, x1, 13); tf_round(x0, x1, 15); tf_round(x0, x1, 26); tf_round(x0, x1, 6);
    x0 += k1;  x1 += ks2 + 1u;
    tf_round(x0, x1, 17); tf_round(x0, x1, 29); tf_round(x0, x1, 16); tf_round(x0, x1, 24);
    x0 += ks2; x1 += k0 + 2u;
    tf_round(x0, x1, 13); tf_round(x0, x1, 15); tf_round(x0, x1, 26); tf_round(x0, x1, 6);
    x0 += k0;  x1 += k1 + 3u;
    tf_round(x0, x1, 17); tf_round(x0, x1, 29); tf_round(x0, x1, 16); tf_round(x0, x1, 24);
    x0 += k1;  x1 += ks2 + 4u;
    tf_round(x0, x1, 13); tf_round(x0, x1, 15); tf_round(x0, x1, 26); tf_round(x0, x1, 6);
    x0 += ks2; x1 += k0 + 5u;
    return x0 ^ x1;
}

// ---------------- Prep: pack (sum_c grid, opacity) into float2 table ----------------
__global__ __launch_bounds__(256) void rf_prep(const float* __restrict__ grid,
                                               const float* __restrict__ opac,
                                               float2* __restrict__ pk) {
    int i = blockIdx.x * blockDim.x + threadIdx.x;
    if (i >= NCELL) return;
    const float* g = grid + (size_t)i * 9;
    float s = 0.0f;
#pragma unroll
    for (int c = 0; c < 9; ++c) s += g[c];
    pk[i] = make_float2(s, opac[i]);
}

// ---------------- Main: one 64-lane wave per ray, one lane per sample ----------------
template <bool PACKED>
__global__ __launch_bounds__(256) void rf_main(const float* __restrict__ x,
                                               const float* __restrict__ d,
                                               const float2* __restrict__ pk,
                                               const float* __restrict__ grid,
                                               const float* __restrict__ opac,
                                               float* __restrict__ out) {
    const int lane = threadIdx.x & 63;
    const int ray = blockIdx.x * (blockDim.x >> 6) + (threadIdx.x >> 6);
    if (ray >= NB_RAYS) return;

    const float ox = x[ray * 3 + 0], oy = x[ray * 3 + 1], oz = x[ray * 3 + 2];
    const float dx = d[ray * 3 + 0], dy = d[ray * 3 + 1], dz = d[ray * 3 + 2];
    const float ivx = 1.0f / dx, ivy = 1.0f / dy, ivz = 1.0f / dz;

    const float INF0 = (float)IDIM * (float)IDIM * (float)IDIM;  // 4096000
    float tmin = -INF0, tmax = INF0;
    {
        float t0 = (0.0f - ox) * ivx, t1 = ((float)IDIM - ox) * ivx;
        tmin = fmaxf(tmin, fminf(t0, t1));
        tmax = fminf(tmax, fmaxf(t0, t1));
        t0 = (0.0f - oy) * ivy; t1 = ((float)IDIM - oy) * ivy;
        tmin = fmaxf(tmin, fminf(t0, t1));
        tmax = fminf(tmax, fmaxf(t0, t1));
        t0 = (0.0f - oz) * ivz; t1 = ((float)IDIM - oz) * ivz;
        tmin = fmaxf(tmin, fminf(t0, t1));
        tmax = fminf(tmax, fmaxf(t0, t1));
    }

    // u via threefry, sample position
    const unsigned flat = (unsigned)ray * 64u + (unsigned)lane;
    const unsigned bits = jax_random_bits(flat);
    const float u = __uint_as_float((bits >> 9) | 0x3f800000u) - 1.0f;
    float t = tmin + u * (tmax - tmin);

    // Bitonic sort ascending across the 64 lanes of the wave
#pragma unroll
    for (int k = 2; k <= 64; k <<= 1) {
#pragma unroll
        for (int j = k >> 1; j > 0; j >>= 1) {
            float p = __shfl_xor(t, j, 64);
            bool up = ((lane & k) == 0);
            bool lower = ((lane & j) == 0);
            t = (up == lower) ? fminf(t, p) : fmaxf(t, p);
        }
    }

    const float tnext = __shfl_down(t, 1, 64);  // garbage at lane 63 (masked later)

    // Sample point + trilerp setup (mirror reference: floor, clip, frac)
    const float px = ox + t * dx, py = oy + t * dy, pz = oz + t * dz;
    float bx = fminf(fmaxf(floorf(px), 0.0f), (float)(IDIM - 1));
    float by = fminf(fmaxf(floorf(py), 0.0f), (float)(IDIM - 1));
    float bz = fminf(fmaxf(floorf(pz), 0.0f), (float)(IDIM - 1));
    const int ix = (int)bx, iy = (int)by, iz = (int)bz;
    const float fx = px - bx, fy = py - by, fz = pz - bz;

    float h = 0.0f, o = 0.0f;
#pragma unroll
    for (int c = 0; c < 8; ++c) {
        const int cx = (c >> 2) & 1, cy = (c >> 1) & 1, cz = c & 1;
        const float w = (cx ? fx : 1.0f - fx) * (cy ? fy : 1.0f - fy) * (cz ? fz : 1.0f - fz);
        const size_t idx = ((size_t)(ix + cx) * GDIM + (size_t)(iy + cy)) * GDIM + (size_t)(iz + cz);
        if (PACKED) {
            const float2 v = pk[idx];
            h += w * v.x;
            o += w * v.y;
        } else {
            const float* g = grid + idx * 9;
            float s = 0.0f;
#pragma unroll
            for (int ch = 0; ch < 9; ++ch) s += g[ch];
            h += w * s;
            o += w * opac[idx];
        }
    }

    // Transmittance accumulation across the wave
    const float delta = tnext - t;
    const float cur = (lane < 63) ? delta * o : 0.0f;

    float inc = cur;  // inclusive prefix sum
#pragma unroll
    for (int off = 1; off < 64; off <<= 1) {
        float n = __shfl_up(inc, off, 64);
        if (lane >= off) inc += n;
    }
    const float excl = inc - cur;
    const float trans = expf(-excl);
    const float colr = 1.0f / (1.0f + expf(-h));
    float contrib = (lane < 63) ? trans * (1.0f - expf(-cur)) * colr : 0.0f;

#pragma unroll
    for (int off = 32; off > 0; off >>= 1) contrib += __shfl_xor(contrib, off, 64);

    if (lane == 0) out[ray] = contrib;
}

extern "C" void kernel_launch(void* const* d_in, const int* in_sizes, int n_in,
                              void* d_out, int out_size, void* d_ws, size_t ws_size,
                              hipStream_t stream) {
    const float* x = (const float*)d_in[0];
    const float* d = (const float*)d_in[1];
    const float* grid = (const float*)d_in[2];
    const float* opac = (const float*)d_in[3];
    float* out = (float*)d_out;

    const size_t need = (size_t)NCELL * sizeof(float2);
    const int waves_per_block = 4;  // 256 threads
    const int nblocks = NB_RAYS / waves_per_block;

    if (ws_size >= need) {
        float2* pk = (float2*)d_ws;
        rf_prep<<<(NCELL + 255) / 256, 256, 0, stream>>>(grid, opac, pk);
        rf_main<true><<<nblocks, 256, 0, stream>>>(x, d, pk, nullptr, nullptr, out);
    } else {
        rf_main<false><<<nblocks, 256, 0, stream>>>(x, d, nullptr, grid, opac, out);
    }
}

// Round 4
// 103.880 us; speedup vs baseline: 1.4764x; 1.4764x over previous
//
#include <hip/hip_runtime.h>
#include <hip/hip_fp16.h>
#include <math.h>

#define IDIM 160
#define GDIM 161
#define NB_SAMPLES 64
#define NB_RAYS 32768
#define NCELL (GDIM * GDIM * GDIM)  // 4173281

// ---------------- Threefry2x32 (JAX-compatible, partitionable path) ----------------
__device__ __forceinline__ unsigned rotl32(unsigned x, unsigned d) {
    return (x << d) | (x >> (32u - d));
}

__device__ __forceinline__ void tf_round(unsigned& x0, unsigned& x1, unsigned r) {
    x0 += x1;
    x1 = rotl32(x1, r);
    x1 ^= x0;
}

__device__ __forceinline__ unsigned jax_random_bits(unsigned idx) {
    const unsigned k0 = 0u, k1 = 42u;
    const unsigned ks2 = k0 ^ k1 ^ 0x1BD11BDAu;
    unsigned x0 = 0u + k0;    // counts_hi + ks0
    unsigned x1 = idx + k1;   // counts_lo + ks1
    tf_round(x0, x1, 13); tf_round(x0, x1, 15); tf_round(x0, x1, 26); tf_round(x0, x1, 6);
    x0 += k1;  x1 += ks2 + 1u;
    tf_round(x0, x1, 17); tf_round(x0, x1, 29); tf_round(x0, x1, 16); tf_round(x0, x1, 24);
    x0 += ks2; x1 += k0 + 2u;
    tf_round(x0, x1, 13); tf_round(x0, x1, 15); tf_round(x0, x1, 26); tf_round(x0, x1, 6);
    x0 += k0;  x1 += k1 + 3u;
    tf_round(x0, x1, 17); tf_round(x0, x1, 29); tf_round(x0, x1, 16); tf_round(x0, x1, 24);
    x0 += k1;  x1 += ks2 + 4u;
    tf_round(x0, x1, 13); tf_round(x0, x1, 15); tf_round(x0, x1, 26); tf_round(x0, x1, 6);
    x0 += ks2; x1 += k0 + 5u;
    return x0 ^ x1;
}

// fp16x2 (packed in u32) -> float2
__device__ __forceinline__ float2 h2f2(unsigned u) {
    const __half2 h = *(const __half2*)&u;
    return __half22float2(h);
}

// ---------------- Prep (quad): each 16B entry(x,y,z) = fp16 (h,o) for cells
// (y..y+1, z..z+1). Slot layout: U[4e + 2*qy + qz]. Cell (x,Y,Z) writes slot
// (qy,qz) of entry (x, Y-qy, Z-qz) for qy,qz in {0,1}; each slot has exactly
// one writer. Entries with y==160 or z==160 are only partially written but
// are never read (base indices are clipped to <=159).
__global__ __launch_bounds__(256) void rf_prep_quad(const float* __restrict__ grid,
                                                    const float* __restrict__ opac,
                                                    unsigned* __restrict__ pk) {
    int i = blockIdx.x * blockDim.x + threadIdx.x;
    if (i >= NCELL) return;
    const int z = i % GDIM;
    const int y = (i / GDIM) % GDIM;
    const float* g = grid + (size_t)i * 9;
    float s = 0.0f;
#pragma unroll
    for (int c = 0; c < 9; ++c) s += g[c];
    const unsigned hs = (unsigned)__half_as_ushort(__float2half(s));
    const unsigned ho = (unsigned)__half_as_ushort(__float2half(opac[i]));
    const unsigned v = hs | (ho << 16);
    const int e4 = 4 * i;
    pk[e4] = v;                                       // slot(0,0) of entry (x,Y,Z)
    if (z > 0) pk[e4 - 3] = v;                        // slot(0,1) of entry (x,Y,Z-1):  4*(i-1)+1
    if (y > 0) pk[e4 - 4 * GDIM + 2] = v;             // slot(1,0) of entry (x,Y-1,Z):  4*(i-GDIM)+2
    if (y > 0 && z > 0) pk[e4 - 4 * GDIM - 1] = v;    // slot(1,1) of entry (x,Y-1,Z-1): 4*(i-GDIM-1)+3
}

// ---------------- Prep (pair fallback): float2 (h_sum, opacity) per cell ----
__global__ __launch_bounds__(256) void rf_prep(const float* __restrict__ grid,
                                               const float* __restrict__ opac,
                                               float2* __restrict__ pk) {
    int i = blockIdx.x * blockDim.x + threadIdx.x;
    if (i >= NCELL) return;
    const float* g = grid + (size_t)i * 9;
    float s = 0.0f;
#pragma unroll
    for (int c = 0; c < 9; ++c) s += g[c];
    pk[i] = make_float2(s, opac[i]);
}

// ---------------- Main: one 64-lane wave per ray, one lane per sample ----------------
// MODE: 0 = fused (read grid directly), 1 = packed float2, 2 = quad fp16
template <int MODE>
__global__ __launch_bounds__(256) void rf_main(const float* __restrict__ x,
                                               const float* __restrict__ d,
                                               const void* __restrict__ table,
                                               const float* __restrict__ grid,
                                               const float* __restrict__ opac,
                                               float* __restrict__ out) {
    const int lane = threadIdx.x & 63;
    const int ray = blockIdx.x * (blockDim.x >> 6) + (threadIdx.x >> 6);
    if (ray >= NB_RAYS) return;

    const float ox = x[ray * 3 + 0], oy = x[ray * 3 + 1], oz = x[ray * 3 + 2];
    const float dx = d[ray * 3 + 0], dy = d[ray * 3 + 1], dz = d[ray * 3 + 2];
    const float ivx = 1.0f / dx, ivy = 1.0f / dy, ivz = 1.0f / dz;

    const float INF0 = (float)IDIM * (float)IDIM * (float)IDIM;  // 4096000
    float tmin = -INF0, tmax = INF0;
    {
        float t0 = (0.0f - ox) * ivx, t1 = ((float)IDIM - ox) * ivx;
        tmin = fmaxf(tmin, fminf(t0, t1));
        tmax = fminf(tmax, fmaxf(t0, t1));
        t0 = (0.0f - oy) * ivy; t1 = ((float)IDIM - oy) * ivy;
        tmin = fmaxf(tmin, fminf(t0, t1));
        tmax = fminf(tmax, fmaxf(t0, t1));
        t0 = (0.0f - oz) * ivz; t1 = ((float)IDIM - oz) * ivz;
        tmin = fmaxf(tmin, fminf(t0, t1));
        tmax = fminf(tmax, fmaxf(t0, t1));
    }

    // u via threefry, sample position
    const unsigned flat = (unsigned)ray * 64u + (unsigned)lane;
    const unsigned bits = jax_random_bits(flat);
    const float u = __uint_as_float((bits >> 9) | 0x3f800000u) - 1.0f;
    float t = tmin + u * (tmax - tmin);

    // Bitonic sort ascending across the 64 lanes of the wave
#pragma unroll
    for (int k = 2; k <= 64; k <<= 1) {
#pragma unroll
        for (int j = k >> 1; j > 0; j >>= 1) {
            float p = __shfl_xor(t, j, 64);
            bool up = ((lane & k) == 0);
            bool lower = ((lane & j) == 0);
            t = (up == lower) ? fminf(t, p) : fmaxf(t, p);
        }
    }

    const float tnext = __shfl_down(t, 1, 64);  // garbage at lane 63 (masked later)

    // Sample point + trilerp setup (mirror reference: floor, clip, frac)
    const float px = ox + t * dx, py = oy + t * dy, pz = oz + t * dz;
    float bx = fminf(fmaxf(floorf(px), 0.0f), (float)(IDIM - 1));
    float by = fminf(fmaxf(floorf(py), 0.0f), (float)(IDIM - 1));
    float bz = fminf(fmaxf(floorf(pz), 0.0f), (float)(IDIM - 1));
    const int ix = (int)bx, iy = (int)by, iz = (int)bz;
    const float fx = px - bx, fy = py - by, fz = pz - bz;

    float h = 0.0f, o = 0.0f;
    if (MODE == 2) {
        const uint4* __restrict__ pkq = (const uint4*)table;
        const float wy0 = 1.0f - fy, wy1 = fy, wz0 = 1.0f - fz, wz1 = fz;
        const size_t e0 = ((size_t)ix * GDIM + (size_t)iy) * GDIM + (size_t)iz;
        const uint4 qa = pkq[e0];
        const uint4 qb = pkq[e0 + (size_t)GDIM * GDIM];
#pragma unroll
        for (int cx = 0; cx < 2; ++cx) {
            const uint4 q = cx ? qb : qa;
            const float wx = cx ? fx : 1.0f - fx;
            const float w00 = wx * wy0 * wz0, w01 = wx * wy0 * wz1;
            const float w10 = wx * wy1 * wz0, w11 = wx * wy1 * wz1;
            float2 f;
            f = h2f2(q.x); h += w00 * f.x; o += w00 * f.y;
            f = h2f2(q.y); h += w01 * f.x; o += w01 * f.y;
            f = h2f2(q.z); h += w10 * f.x; o += w10 * f.y;
            f = h2f2(q.w); h += w11 * f.x; o += w11 * f.y;
        }
    } else {
#pragma unroll
        for (int c = 0; c < 8; ++c) {
            const int cx = (c >> 2) & 1, cy = (c >> 1) & 1, cz = c & 1;
            const float w = (cx ? fx : 1.0f - fx) * (cy ? fy : 1.0f - fy) * (cz ? fz : 1.0f - fz);
            const size_t idx = ((size_t)(ix + cx) * GDIM + (size_t)(iy + cy)) * GDIM + (size_t)(iz + cz);
            if (MODE == 1) {
                const float2 v = ((const float2*)table)[idx];
                h += w * v.x;
                o += w * v.y;
            } else {
                const float* g = grid + idx * 9;
                float s = 0.0f;
#pragma unroll
                for (int ch = 0; ch < 9; ++ch) s += g[ch];
                h += w * s;
                o += w * opac[idx];
            }
        }
    }

    // Transmittance accumulation across the wave
    const float delta = tnext - t;
    const float cur = (lane < 63) ? delta * o : 0.0f;

    float inc = cur;  // inclusive prefix sum
#pragma unroll
    for (int off = 1; off < 64; off <<= 1) {
        float n = __shfl_up(inc, off, 64);
        if (lane >= off) inc += n;
    }
    const float excl = inc - cur;
    const float trans = expf(-excl);
    const float colr = 1.0f / (1.0f + expf(-h));
    float contrib = (lane < 63) ? trans * (1.0f - expf(-cur)) * colr : 0.0f;

#pragma unroll
    for (int off = 32; off > 0; off >>= 1) contrib += __shfl_xor(contrib, off, 64);

    if (lane == 0) out[ray] = contrib;
}

extern "C" void kernel_launch(void* const* d_in, const int* in_sizes, int n_in,
                              void* d_out, int out_size, void* d_ws, size_t ws_size,
                              hipStream_t stream) {
    const float* x = (const float*)d_in[0];
    const float* d = (const float*)d_in[1];
    const float* grid = (const float*)d_in[2];
    const float* opac = (const float*)d_in[3];
    float* out = (float*)d_out;

    const size_t need_quad = (size_t)NCELL * 16;  // ~66.8 MB
    const size_t need_pair = (size_t)NCELL * 8;   // ~33.4 MB
    const int waves_per_block = 4;  // 256 threads
    const int nblocks = NB_RAYS / waves_per_block;
    const int prep_blocks = (NCELL + 255) / 256;

    if (ws_size >= need_quad) {
        unsigned* pk = (unsigned*)d_ws;
        rf_prep_quad<<<prep_blocks, 256, 0, stream>>>(grid, opac, pk);
        rf_main<2><<<nblocks, 256, 0, stream>>>(x, d, pk, nullptr, nullptr, out);
    } else if (ws_size >= need_pair) {
        float2* pk = (float2*)d_ws;
        rf_prep<<<prep_blocks, 256, 0, stream>>>(grid, opac, pk);
        rf_main<1><<<nblocks, 256, 0, stream>>>(x, d, pk, nullptr, nullptr, out);
    } else {
        rf_main<0><<<nblocks, 256, 0, stream>>>(x, d, nullptr, grid, opac, out);
    }
}

// Round 5
// 98.486 us; speedup vs baseline: 1.5573x; 1.0548x over previous
//
#include <hip/hip_runtime.h>
#include <hip/hip_fp16.h>
#include <math.h>

#define IDIM 160
#define GDIM 161
#define NB_SAMPLES 64
#define NB_RAYS 32768
#define NCELL (GDIM * GDIM * GDIM)  // 4173281
#define NQUAD (NCELL / 4)           // 1043320 full 4-cell groups (+1 tail cell)

// ---------------- Threefry2x32 (JAX-compatible, partitionable path) ----------------
__device__ __forceinline__ unsigned rotl32(unsigned x, unsigned d) {
    return (x << d) | (x >> (32u - d));
}

__device__ __forceinline__ void tf_round(unsigned& x0, unsigned& x1, unsigned r) {
    x0 += x1;
    x1 = rotl32(x1, r);
    x1 ^= x0;
}

__device__ __forceinline__ unsigned jax_random_bits(unsigned idx) {
    const unsigned k0 = 0u, k1 = 42u;
    const unsigned ks2 = k0 ^ k1 ^ 0x1BD11BDAu;
    unsigned x0 = 0u + k0;    // counts_hi + ks0
    unsigned x1 = idx + k1;   // counts_lo + ks1
    tf_round(x0, x1, 13); tf_round(x0, x1, 15); tf_round(x0, x1, 26); tf_round(x0, x1, 6);
    x0 += k1;  x1 += ks2 + 1u;
    tf_round(x0, x1, 17); tf_round(x0, x1, 29); tf_round(x0, x1, 16); tf_round(x0, x1, 24);
    x0 += ks2; x1 += k0 + 2u;
    tf_round(x0, x1, 13); tf_round(x0, x1, 15); tf_round(x0, x1, 26); tf_round(x0, x1, 6);
    x0 += k0;  x1 += k1 + 3u;
    tf_round(x0, x1, 17); tf_round(x0, x1, 29); tf_round(x0, x1, 16); tf_round(x0, x1, 24);
    x0 += k1;  x1 += ks2 + 4u;
    tf_round(x0, x1, 13); tf_round(x0, x1, 15); tf_round(x0, x1, 26); tf_round(x0, x1, 6);
    x0 += ks2; x1 += k0 + 5u;
    return x0 ^ x1;
}

// fp16x2 (packed in u32) -> float2
__device__ __forceinline__ float2 h2f2(unsigned u) {
    const __half2 h = *(const __half2*)&u;
    return __half22float2(h);
}

__device__ __forceinline__ unsigned pack_ho(float s, float op) {
    const unsigned hs = (unsigned)__half_as_ushort(__float2half(s));
    const unsigned ho = (unsigned)__half_as_ushort(__float2half(op));
    return hs | (ho << 16);
}

// ---------------- Pass A: per-cell packed fp16 (h_sum, opacity), fully vectorized.
// Thread j handles cells 4j..4j+3: 9 aligned float4 grid loads + 1 float4 opac
// load -> one uint4 store. One extra thread (j == NQUAD) handles the tail cell.
__global__ __launch_bounds__(256) void rf_cells(const float4* __restrict__ grid4,
                                                const float* __restrict__ opac,
                                                unsigned* __restrict__ v) {
    const int j = blockIdx.x * blockDim.x + threadIdx.x;
    if (j < NQUAD) {
        const float4* gp = grid4 + (size_t)j * 9;
        float f[36];
#pragma unroll
        for (int q = 0; q < 9; ++q) {
            const float4 t = gp[q];
            f[4 * q + 0] = t.x; f[4 * q + 1] = t.y; f[4 * q + 2] = t.z; f[4 * q + 3] = t.w;
        }
        const float4 op = *(const float4*)(opac + (size_t)j * 4);
        float s[4];
#pragma unroll
        for (int k = 0; k < 4; ++k) {
            float acc = 0.0f;
#pragma unroll
            for (int c = 0; c < 9; ++c) acc += f[9 * k + c];
            s[k] = acc;
        }
        uint4 o;
        o.x = pack_ho(s[0], op.x);
        o.y = pack_ho(s[1], op.y);
        o.z = pack_ho(s[2], op.z);
        o.w = pack_ho(s[3], op.w);
        *(uint4*)(v + (size_t)j * 4) = o;
    } else if (j == NQUAD) {
        // tail cell NCELL-1
        const size_t i = (size_t)NCELL - 1;
        const float* g = (const float*)grid4 + i * 9;
        float acc = 0.0f;
#pragma unroll
        for (int c = 0; c < 9; ++c) acc += g[c];
        v[i] = pack_ho(acc, opac[i]);
    }
}

// ---------------- Pass B: build quad table. Entry e = fp16 (h,o) for cells
// (y..y+1, z..z+1): slots {v[e], v[e+1], v[e+GDIM], v[e+GDIM+1]}. All loads
// and the uint4 store are wave-coalesced. Entries with y==160/z==160 are
// never read by main (base clipped to <=159); clamped reads keep them safe.
__global__ __launch_bounds__(256) void rf_quad(const unsigned* __restrict__ v,
                                               uint4* __restrict__ pk) {
    const int e = blockIdx.x * blockDim.x + threadIdx.x;
    if (e >= NCELL) return;
    const int m = NCELL - 1;
    const unsigned a = v[e];
    const unsigned b = v[min(e + 1, m)];
    const unsigned c = v[min(e + GDIM, m)];
    const unsigned w = v[min(e + GDIM + 1, m)];
    pk[e] = make_uint4(a, b, c, w);
}

// ---------------- Legacy scatter prep (fallback when ws fits quad but not quad+v)
__global__ __launch_bounds__(256) void rf_prep_quad(const float* __restrict__ grid,
                                                    const float* __restrict__ opac,
                                                    unsigned* __restrict__ pk) {
    int i = blockIdx.x * blockDim.x + threadIdx.x;
    if (i >= NCELL) return;
    const int z = i % GDIM;
    const int y = (i / GDIM) % GDIM;
    const float* g = grid + (size_t)i * 9;
    float s = 0.0f;
#pragma unroll
    for (int c = 0; c < 9; ++c) s += g[c];
    const unsigned vv = pack_ho(s, opac[i]);
    const int e4 = 4 * i;
    pk[e4] = vv;
    if (z > 0) pk[e4 - 3] = vv;
    if (y > 0) pk[e4 - 4 * GDIM + 2] = vv;
    if (y > 0 && z > 0) pk[e4 - 4 * GDIM - 1] = vv;
}

// ---------------- Prep (pair fallback): float2 (h_sum, opacity) per cell ----
__global__ __launch_bounds__(256) void rf_prep(const float* __restrict__ grid,
                                               const float* __restrict__ opac,
                                               float2* __restrict__ pk) {
    int i = blockIdx.x * blockDim.x + threadIdx.x;
    if (i >= NCELL) return;
    const float* g = grid + (size_t)i * 9;
    float s = 0.0f;
#pragma unroll
    for (int c = 0; c < 9; ++c) s += g[c];
    pk[i] = make_float2(s, opac[i]);
}

// ---------------- Main: one 64-lane wave per ray, one lane per sample ----------------
// MODE: 0 = fused (read grid directly), 1 = packed float2, 2 = quad fp16
template <int MODE>
__global__ __launch_bounds__(256) void rf_main(const float* __restrict__ x,
                                               const float* __restrict__ d,
                                               const void* __restrict__ table,
                                               const float* __restrict__ grid,
                                               const float* __restrict__ opac,
                                               float* __restrict__ out) {
    const int lane = threadIdx.x & 63;
    const int ray = blockIdx.x * (blockDim.x >> 6) + (threadIdx.x >> 6);
    if (ray >= NB_RAYS) return;

    const float ox = x[ray * 3 + 0], oy = x[ray * 3 + 1], oz = x[ray * 3 + 2];
    const float dx = d[ray * 3 + 0], dy = d[ray * 3 + 1], dz = d[ray * 3 + 2];
    const float ivx = 1.0f / dx, ivy = 1.0f / dy, ivz = 1.0f / dz;

    const float INF0 = (float)IDIM * (float)IDIM * (float)IDIM;  // 4096000
    float tmin = -INF0, tmax = INF0;
    {
        float t0 = (0.0f - ox) * ivx, t1 = ((float)IDIM - ox) * ivx;
        tmin = fmaxf(tmin, fminf(t0, t1));
        tmax = fminf(tmax, fmaxf(t0, t1));
        t0 = (0.0f - oy) * ivy; t1 = ((float)IDIM - oy) * ivy;
        tmin = fmaxf(tmin, fminf(t0, t1));
        tmax = fminf(tmax, fmaxf(t0, t1));
        t0 = (0.0f - oz) * ivz; t1 = ((float)IDIM - oz) * ivz;
        tmin = fmaxf(tmin, fminf(t0, t1));
        tmax = fminf(tmax, fmaxf(t0, t1));
    }

    // u via threefry, sample position
    const unsigned flat = (unsigned)ray * 64u + (unsigned)lane;
    const unsigned bits = jax_random_bits(flat);
    const float u = __uint_as_float((bits >> 9) | 0x3f800000u) - 1.0f;
    float t = tmin + u * (tmax - tmin);

    // Bitonic sort ascending across the 64 lanes of the wave
#pragma unroll
    for (int k = 2; k <= 64; k <<= 1) {
#pragma unroll
        for (int j = k >> 1; j > 0; j >>= 1) {
            float p = __shfl_xor(t, j, 64);
            bool up = ((lane & k) == 0);
            bool lower = ((lane & j) == 0);
            t = (up == lower) ? fminf(t, p) : fmaxf(t, p);
        }
    }

    const float tnext = __shfl_down(t, 1, 64);  // garbage at lane 63 (masked later)

    // Sample point + trilerp setup (mirror reference: floor, clip, frac)
    const float px = ox + t * dx, py = oy + t * dy, pz = oz + t * dz;
    float bx = fminf(fmaxf(floorf(px), 0.0f), (float)(IDIM - 1));
    float by = fminf(fmaxf(floorf(py), 0.0f), (float)(IDIM - 1));
    float bz = fminf(fmaxf(floorf(pz), 0.0f), (float)(IDIM - 1));
    const int ix = (int)bx, iy = (int)by, iz = (int)bz;
    const float fx = px - bx, fy = py - by, fz = pz - bz;

    float h = 0.0f, o = 0.0f;
    if (MODE == 2) {
        const uint4* __restrict__ pkq = (const uint4*)table;
        const float wy0 = 1.0f - fy, wy1 = fy, wz0 = 1.0f - fz, wz1 = fz;
        const size_t e0 = ((size_t)ix * GDIM + (size_t)iy) * GDIM + (size_t)iz;
        const uint4 qa = pkq[e0];
        const uint4 qb = pkq[e0 + (size_t)GDIM * GDIM];
#pragma unroll
        for (int cx = 0; cx < 2; ++cx) {
            const uint4 q = cx ? qb : qa;
            const float wx = cx ? fx : 1.0f - fx;
            const float w00 = wx * wy0 * wz0, w01 = wx * wy0 * wz1;
            const float w10 = wx * wy1 * wz0, w11 = wx * wy1 * wz1;
            float2 f;
            f = h2f2(q.x); h += w00 * f.x; o += w00 * f.y;
            f = h2f2(q.y); h += w01 * f.x; o += w01 * f.y;
            f = h2f2(q.z); h += w10 * f.x; o += w10 * f.y;
            f = h2f2(q.w); h += w11 * f.x; o += w11 * f.y;
        }
    } else {
#pragma unroll
        for (int c = 0; c < 8; ++c) {
            const int cx = (c >> 2) & 1, cy = (c >> 1) & 1, cz = c & 1;
            const float w = (cx ? fx : 1.0f - fx) * (cy ? fy : 1.0f - fy) * (cz ? fz : 1.0f - fz);
            const size_t idx = ((size_t)(ix + cx) * GDIM + (size_t)(iy + cy)) * GDIM + (size_t)(iz + cz);
            if (MODE == 1) {
                const float2 v = ((const float2*)table)[idx];
                h += w * v.x;
                o += w * v.y;
            } else {
                const float* g = grid + idx * 9;
                float s = 0.0f;
#pragma unroll
                for (int ch = 0; ch < 9; ++ch) s += g[ch];
                h += w * s;
                o += w * opac[idx];
            }
        }
    }

    // Transmittance accumulation across the wave
    const float delta = tnext - t;
    const float cur = (lane < 63) ? delta * o : 0.0f;

    float inc = cur;  // inclusive prefix sum
#pragma unroll
    for (int off = 1; off < 64; off <<= 1) {
        float n = __shfl_up(inc, off, 64);
        if (lane >= off) inc += n;
    }
    const float excl = inc - cur;
    const float trans = expf(-excl);
    const float colr = 1.0f / (1.0f + expf(-h));
    float contrib = (lane < 63) ? trans * (1.0f - expf(-cur)) * colr : 0.0f;

#pragma unroll
    for (int off = 32; off > 0; off >>= 1) contrib += __shfl_xor(contrib, off, 64);

    if (lane == 0) out[ray] = contrib;
}

extern "C" void kernel_launch(void* const* d_in, const int* in_sizes, int n_in,
                              void* d_out, int out_size, void* d_ws, size_t ws_size,
                              hipStream_t stream) {
    const float* x = (const float*)d_in[0];
    const float* d = (const float*)d_in[1];
    const float* grid = (const float*)d_in[2];
    const float* opac = (const float*)d_in[3];
    float* out = (float*)d_out;

    const size_t need_quad2 = (size_t)NCELL * 20;  // quad table + cell table (~83.5 MB)
    const size_t need_quad  = (size_t)NCELL * 16;  // ~66.8 MB
    const size_t need_pair  = (size_t)NCELL * 8;   // ~33.4 MB
    const int waves_per_block = 4;  // 256 threads
    const int nblocks = NB_RAYS / waves_per_block;
    const int prep_blocks = (NCELL + 255) / 256;

    if (ws_size >= need_quad2) {
        unsigned* pk = (unsigned*)d_ws;
        unsigned* v = (unsigned*)((char*)d_ws + (size_t)NCELL * 16);
        rf_cells<<<(NQUAD + 1 + 255) / 256, 256, 0, stream>>>((const float4*)grid, opac, v);
        rf_quad<<<prep_blocks, 256, 0, stream>>>(v, (uint4*)pk);
        rf_main<2><<<nblocks, 256, 0, stream>>>(x, d, pk, nullptr, nullptr, out);
    } else if (ws_size >= need_quad) {
        unsigned* pk = (unsigned*)d_ws;
        rf_prep_quad<<<prep_blocks, 256, 0, stream>>>(grid, opac, pk);
        rf_main<2><<<nblocks, 256, 0, stream>>>(x, d, pk, nullptr, nullptr, out);
    } else if (ws_size >= need_pair) {
        float2* pk = (float2*)d_ws;
        rf_prep<<<prep_blocks, 256, 0, stream>>>(grid, opac, pk);
        rf_main<1><<<nblocks, 256, 0, stream>>>(x, d, pk, nullptr, nullptr, out);
    } else {
        rf_main<0><<<nblocks, 256, 0, stream>>>(x, d, nullptr, grid, opac, out);
    }
}